// Round 1
// baseline (2525.396 us; speedup 1.0000x reference)
//
#include <hip/hip_runtime.h>

#define N_USERS 100000
#define N_ITEMS 50000
#define N_NODES 150000
#define N_EDGES 1500000
#define EMBED 100
#define BATCH 4096

// ---------------- SpMM: out += A * X  (atomic segment-sum) ----------------
// 8 edges per 256-thread block, 32 lanes per edge.
template<int F>
__global__ __launch_bounds__(256) void spmm_kernel(
    const int* __restrict__ rows, const int* __restrict__ cols,
    const float* __restrict__ vals, int E,
    const float* __restrict__ Xu, const float* __restrict__ Xi, int split,
    float* __restrict__ out)
{
    int e = blockIdx.x * 8 + (threadIdx.x >> 5);
    if (e >= E) return;
    int lane = threadIdx.x & 31;
    int r = rows[e];
    int c = cols[e];
    float v = vals[e];
    const float* x = (c < split) ? (Xu + (size_t)c * F)
                                 : (Xi + (size_t)(c - split) * F);
    float* o = out + (size_t)r * F;
    for (int f = lane; f < F; f += 32)
        atomicAdd(&o[f], v * x[f]);
}

// ---------------- SpMM2: out += A * (Lx .* X)  (fused elementwise) --------
template<int F>
__global__ __launch_bounds__(256) void spmm2_kernel(
    const int* __restrict__ rows, const int* __restrict__ cols,
    const float* __restrict__ vals, int E,
    const float* __restrict__ Lx,
    const float* __restrict__ Xu, const float* __restrict__ Xi, int split,
    float* __restrict__ out)
{
    int e = blockIdx.x * 8 + (threadIdx.x >> 5);
    if (e >= E) return;
    int lane = threadIdx.x & 31;
    int r = rows[e];
    int c = cols[e];
    float v = vals[e];
    const float* x = (c < split) ? (Xu + (size_t)c * F)
                                 : (Xi + (size_t)(c - split) * F);
    const float* l = Lx + (size_t)c * F;
    float* o = out + (size_t)r * F;
    for (int f = lane; f < F; f += 32)
        atomicAdd(&o[f], v * l[f] * x[f]);
}

// ------------- Fused GNN linear: out = relu((Lx+X)@W + S2@Wi + b + bi) ----
// TPR threads cooperate on one row, each owns M/TPR outputs. W, Wi in LDS.
template<int K, int M, int TPR>
__global__ __launch_bounds__(256) void gemm_fused(
    const float* __restrict__ Lx,
    const float* __restrict__ Xu, const float* __restrict__ Xi, int split,
    const float* __restrict__ S2,
    const float* __restrict__ W, const float* __restrict__ b,
    const float* __restrict__ Wi, const float* __restrict__ bi,
    float* __restrict__ out, int N)
{
    __shared__ float sW[K * M];
    __shared__ float sWi[K * M];
    for (int i = threadIdx.x; i < K * M; i += 256) {
        sW[i]  = W[i];
        sWi[i] = Wi[i];
    }
    __syncthreads();

    constexpr int RPB = 256 / TPR;
    constexpr int MT  = M / TPR;
    int r = blockIdx.x * RPB + (int)threadIdx.x / TPR;
    int mBase = ((int)threadIdx.x % TPR) * MT;
    if (r >= N) return;

    const float* xrow = (r < split) ? (Xu + (size_t)r * K)
                                    : (Xi + (size_t)(r - split) * K);
    const float* lrow = Lx + (size_t)r * K;
    const float* srow = S2 + (size_t)r * K;

    float acc[MT];
#pragma unroll
    for (int m = 0; m < MT; m++) acc[m] = 0.0f;

    static_assert(K % 4 == 0, "K must be multiple of 4");
    for (int k4 = 0; k4 < K; k4 += 4) {
        float4 lv = *(const float4*)(lrow + k4);
        float4 xv = *(const float4*)(xrow + k4);
        float4 sv = *(const float4*)(srow + k4);
        float a[4] = {lv.x + xv.x, lv.y + xv.y, lv.z + xv.z, lv.w + xv.w};
        float s[4] = {sv.x, sv.y, sv.z, sv.w};
#pragma unroll
        for (int kk = 0; kk < 4; kk++) {
            const float* wk  = &sW[(k4 + kk) * M + mBase];
            const float* wik = &sWi[(k4 + kk) * M + mBase];
#pragma unroll
            for (int m = 0; m < MT; m++)
                acc[m] = fmaf(a[kk], wk[m], fmaf(s[kk], wik[m], acc[m]));
        }
    }

    float* orow = out + (size_t)r * M + mBase;
#pragma unroll
    for (int m = 0; m < MT; m++)
        orow[m] = fmaxf(acc[m] + b[mBase + m] + bi[mBase + m], 0.0f);
}

// ------------- Plain MLP GEMM: out = (relu?)(A@W + b) ---------------------
template<int K, int M, int TPR, bool RELU>
__global__ __launch_bounds__(256) void mlp_gemm(
    const float* __restrict__ A,
    const float* __restrict__ W, const float* __restrict__ b,
    float* __restrict__ out, int N)
{
    __shared__ float sW[K * M];
    for (int i = threadIdx.x; i < K * M; i += 256) sW[i] = W[i];
    __syncthreads();

    constexpr int RPB = 256 / TPR;
    constexpr int MT  = M / TPR;
    int r = blockIdx.x * RPB + (int)threadIdx.x / TPR;
    int mBase = ((int)threadIdx.x % TPR) * MT;
    if (r >= N) return;

    const float* arow = A + (size_t)r * K;
    float acc[MT];
#pragma unroll
    for (int m = 0; m < MT; m++) acc[m] = 0.0f;

    for (int k = 0; k < K; k++) {
        float a = arow[k];
#pragma unroll
        for (int m = 0; m < MT; m++)
            acc[m] = fmaf(a, sW[k * M + mBase + m], acc[m]);
    }

    float* orow = out + (size_t)r * M + mBase;
#pragma unroll
    for (int m = 0; m < MT; m++) {
        float vv = acc[m] + b[mBase + m];
        orow[m] = RELU ? fmaxf(vv, 0.0f) : vv;
    }
}

// ------------- Gather final embeddings into [BATCH, 460] ------------------
__global__ __launch_bounds__(128) void gather_embd(
    const int* __restrict__ userIdx, const int* __restrict__ itemIdx,
    const float* __restrict__ uE, const float* __restrict__ iE,
    const float* __restrict__ f1, const float* __restrict__ f2,
    float* __restrict__ emb)
{
    int bi = blockIdx.x;
    int u  = userIdx[bi];
    int it = itemIdx[bi];
    float* orow = emb + (size_t)bi * 460;
    for (int c = threadIdx.x; c < 460; c += 128) {
        float val;
        if (c < 100) {
            val = (u < N_USERS) ? uE[(size_t)u * 100 + c]
                                : iE[(size_t)(u - N_USERS) * 100 + c];
        } else if (c < 180) {
            val = f1[(size_t)u * 80 + (c - 100)];
        } else if (c < 230) {
            val = f2[(size_t)u * 50 + (c - 180)];
        } else if (c < 330) {
            int cc = c - 230;
            val = (it < N_USERS) ? uE[(size_t)it * 100 + cc]
                                 : iE[(size_t)(it - N_USERS) * 100 + cc];
        } else if (c < 410) {
            val = f1[(size_t)it * 80 + (c - 330)];
        } else {
            val = f2[(size_t)it * 50 + (c - 410)];
        }
        orow[c] = val;
    }
}

extern "C" void kernel_launch(void* const* d_in, const int* in_sizes, int n_in,
                              void* d_out, int out_size, void* d_ws, size_t ws_size,
                              hipStream_t stream) {
    const int*   userIdx = (const int*)d_in[0];
    const int*   itemIdx = (const int*)d_in[1];
    const int*   rows    = (const int*)d_in[2];
    const int*   cols    = (const int*)d_in[3];
    const float* vals    = (const float*)d_in[4];
    const float* uEmbd   = (const float*)d_in[5];
    const float* iEmbd   = (const float*)d_in[6];
    const float* w1      = (const float*)d_in[7];
    const float* b1      = (const float*)d_in[8];
    const float* wi1     = (const float*)d_in[9];
    const float* bi1     = (const float*)d_in[10];
    const float* w2      = (const float*)d_in[11];
    const float* b2      = (const float*)d_in[12];
    const float* wi2     = (const float*)d_in[13];
    const float* bi2     = (const float*)d_in[14];
    const float* t1w     = (const float*)d_in[15];
    const float* t1b     = (const float*)d_in[16];
    const float* t2w     = (const float*)d_in[17];
    const float* t2b     = (const float*)d_in[18];
    const float* t3w     = (const float*)d_in[19];
    const float* t3b     = (const float*)d_in[20];

    float* ws = (float*)d_ws;
    float* B1  = ws;                        // 150000*100 = 15,000,000
    float* B2  = B1 + 15000000;             // 15,000,000
    float* F1  = B2 + 15000000;             // 150000*80 = 12,000,000
    float* F2  = F1 + 12000000;             // 150000*50 = 7,500,000
    float* EMB = F2 + 7500000;              // 4096*460  = 1,884,160
    float* H1  = EMB + 1884160;             // 4096*64   = 262,144
    float* H2  = H1 + 262144;               // 4096*32   = 131,072

    const int E = N_EDGES;
    dim3 blk(256);
    int spmmGrid = (E + 7) / 8;

    // ---------------- Layer 1 (F = 100) ----------------
    hipMemsetAsync(B1, 0, (size_t)N_NODES * 100 * sizeof(float), stream);
    hipMemsetAsync(B2, 0, (size_t)N_NODES * 100 * sizeof(float), stream);

    spmm_kernel<100><<<spmmGrid, blk, 0, stream>>>(
        rows, cols, vals, E, uEmbd, iEmbd, N_USERS, B1);

    spmm2_kernel<100><<<spmmGrid, blk, 0, stream>>>(
        rows, cols, vals, E, B1, uEmbd, iEmbd, N_USERS, B2);

    {   // F1 = relu((B1 + feats)@w1 + B2@wi1 + b1 + bi1)
        constexpr int TPR = 4;               // 64 rows/block
        int grid = (N_NODES + (256 / TPR) - 1) / (256 / TPR);
        gemm_fused<100, 80, TPR><<<grid, blk, 0, stream>>>(
            B1, uEmbd, iEmbd, N_USERS, B2, w1, b1, wi1, bi1, F1, N_NODES);
    }

    // ---------------- Layer 2 (F = 80) ----------------
    hipMemsetAsync(B1, 0, (size_t)N_NODES * 80 * sizeof(float), stream);
    hipMemsetAsync(B2, 0, (size_t)N_NODES * 80 * sizeof(float), stream);

    spmm_kernel<80><<<spmmGrid, blk, 0, stream>>>(
        rows, cols, vals, E, F1, F1, N_NODES, B1);

    spmm2_kernel<80><<<spmmGrid, blk, 0, stream>>>(
        rows, cols, vals, E, B1, F1, F1, N_NODES, B2);

    {   // F2 = relu((B1 + F1)@w2 + B2@wi2 + b2 + bi2)
        constexpr int TPR = 2;               // 128 rows/block
        int grid = (N_NODES + (256 / TPR) - 1) / (256 / TPR);
        gemm_fused<80, 50, TPR><<<grid, blk, 0, stream>>>(
            B1, F1, F1, N_NODES, B2, w2, b2, wi2, bi2, F2, N_NODES);
    }

    // ---------------- Gather + MLP ----------------
    gather_embd<<<BATCH, dim3(128), 0, stream>>>(
        userIdx, itemIdx, uEmbd, iEmbd, F1, F2, EMB);

    {   // H1 = relu(EMB @ t1w + t1b)   [4096,460]@[460,64]
        constexpr int TPR = 8;               // 32 rows/block
        int grid = (BATCH + (256 / TPR) - 1) / (256 / TPR);
        mlp_gemm<460, 64, TPR, true><<<grid, blk, 0, stream>>>(
            EMB, t1w, t1b, H1, BATCH);
    }
    {   // H2 = EMB2 = H1 @ t2w + t2b   [4096,64]@[64,32]
        constexpr int TPR = 4;               // 64 rows/block
        int grid = (BATCH + (256 / TPR) - 1) / (256 / TPR);
        mlp_gemm<64, 32, TPR, false><<<grid, blk, 0, stream>>>(
            H1, t2w, t2b, H2, BATCH);
    }
    {   // out = H2 @ t3w + t3b         [4096,32]@[32,1]
        constexpr int TPR = 1;               // 256 rows/block
        int grid = (BATCH + 255) / 256;
        mlp_gemm<32, 1, TPR, false><<<grid, blk, 0, stream>>>(
            H2, t3w, t3b, (float*)d_out, BATCH);
    }
}

// Round 2
// 956.061 us; speedup vs baseline: 2.6415x; 2.6415x over previous
//
#include <hip/hip_runtime.h>

#define N_USERS 100000
#define N_ITEMS 50000
#define N_NODES 150000
#define N_EDGES 1500000
#define EMBED 100
#define BATCH 4096

// ======================= CSR construction =======================

__global__ __launch_bounds__(256) void hist_kernel(
    const int* __restrict__ rows, int* __restrict__ deg, int E)
{
    int e = blockIdx.x * 256 + threadIdx.x;
    if (e < E) atomicAdd(&deg[rows[e]], 1);
}

// per-block exclusive scan of deg -> ptr (block-local); block totals -> bsum
__global__ __launch_bounds__(256) void scan_block(
    const int* __restrict__ deg, int* __restrict__ ptr,
    int* __restrict__ bsum, int n)
{
    __shared__ int s[256];
    int t = threadIdx.x;
    int i = blockIdx.x * 256 + t;
    int v = (i < n) ? deg[i] : 0;
    s[t] = v; __syncthreads();
    for (int off = 1; off < 256; off <<= 1) {
        int x = (t >= off) ? s[t - off] : 0;
        __syncthreads();
        s[t] += x;
        __syncthreads();
    }
    if (i < n) ptr[i] = s[t] - v;          // block-local exclusive
    if (t == 255) bsum[blockIdx.x] = s[255];
}

// single-block exclusive scan of bsum (nb <= 1024)
__global__ __launch_bounds__(1024) void scan_tops(int* __restrict__ bsum, int nb)
{
    __shared__ int s[1024];
    int t = threadIdx.x;
    int v = (t < nb) ? bsum[t] : 0;
    s[t] = v; __syncthreads();
    for (int off = 1; off < 1024; off <<= 1) {
        int x = (t >= off) ? s[t - off] : 0;
        __syncthreads();
        s[t] += x;
        __syncthreads();
    }
    if (t < nb) bsum[t] = s[t] - v;        // exclusive
}

__global__ __launch_bounds__(256) void scan_apply(
    int* __restrict__ ptr, const int* __restrict__ bsum,
    int* __restrict__ pos, int n)
{
    int i = blockIdx.x * 256 + threadIdx.x;
    if (i < n) {
        int p = ptr[i] + bsum[i >> 8];
        ptr[i] = p;
        pos[i] = p;
    }
}

__global__ __launch_bounds__(256) void scatter_edges(
    const int* __restrict__ rows, const int* __restrict__ cols,
    const float* __restrict__ vals, int* __restrict__ pos,
    int2* __restrict__ ep, int E)
{
    int e = blockIdx.x * 256 + threadIdx.x;
    if (e < E) {
        int r = rows[e];
        int p = atomicAdd(&pos[r], 1);
        ep[p] = make_int2(cols[e], __float_as_int(vals[e]));
    }
}

// ======================= CSR SpMM =======================
// One 64-lane wave per row. Lane covers feature {lane, lane+64}.
// out[row] = sum_e val_e * X[col_e]   (X split across Xu/Xi)
template<int F>
__global__ __launch_bounds__(256) void spmm_csr_x(
    const int* __restrict__ ptr, const int* __restrict__ deg,
    const int2* __restrict__ ep,
    const float* __restrict__ Xu, const float* __restrict__ Xi, int split,
    float* __restrict__ out, int N)
{
    int row = blockIdx.x * 4 + ((int)threadIdx.x >> 6);
    if (row >= N) return;
    int lane = threadIdx.x & 63;
    int st = ptr[row], d = deg[row];
    float a0 = 0.f, a1 = 0.f;
    for (int j = 0; j < d; j++) {
        int2 e = ep[st + j];
        int c = e.x; float v = __int_as_float(e.y);
        const float* x = (c < split) ? (Xu + (size_t)c * F)
                                     : (Xi + (size_t)(c - split) * F);
        a0 = fmaf(v, x[lane], a0);
        if (F > 64) { if (lane < F - 64) a1 = fmaf(v, x[lane + 64], a1); }
    }
    float* o = out + (size_t)row * F;
    o[lane] = a0;
    if (F > 64) { if (lane < F - 64) o[lane + 64] = a1; }
}

// out[row] = sum_e val_e * (Lx[col_e] .* X[col_e])   (X split)
template<int F>
__global__ __launch_bounds__(256) void spmm_csr_inter_x(
    const int* __restrict__ ptr, const int* __restrict__ deg,
    const int2* __restrict__ ep,
    const float* __restrict__ Lx,
    const float* __restrict__ Xu, const float* __restrict__ Xi, int split,
    float* __restrict__ out, int N)
{
    int row = blockIdx.x * 4 + ((int)threadIdx.x >> 6);
    if (row >= N) return;
    int lane = threadIdx.x & 63;
    int st = ptr[row], d = deg[row];
    float a0 = 0.f, a1 = 0.f;
    for (int j = 0; j < d; j++) {
        int2 e = ep[st + j];
        int c = e.x; float v = __int_as_float(e.y);
        const float* x = (c < split) ? (Xu + (size_t)c * F)
                                     : (Xi + (size_t)(c - split) * F);
        const float* l = Lx + (size_t)c * F;
        a0 = fmaf(v, l[lane] * x[lane], a0);
        if (F > 64) { if (lane < F - 64) a1 = fmaf(v, l[lane + 64] * x[lane + 64], a1); }
    }
    float* o = out + (size_t)row * F;
    o[lane] = a0;
    if (F > 64) { if (lane < F - 64) o[lane + 64] = a1; }
}

// Layer-2 pass 4, restricted to sampled rows. out is COMPACT [2*BATCH][F].
template<int F>
__global__ __launch_bounds__(256) void spmm_csr_inter_sel(
    const int* __restrict__ ptr, const int* __restrict__ deg,
    const int2* __restrict__ ep,
    const float* __restrict__ Lx, const float* __restrict__ X,
    const int* __restrict__ userIdx, const int* __restrict__ itemIdx,
    float* __restrict__ outC)
{
    int i = blockIdx.x * 4 + ((int)threadIdx.x >> 6);
    if (i >= 2 * BATCH) return;
    int row = (i < BATCH) ? userIdx[i] : itemIdx[i - BATCH];
    int lane = threadIdx.x & 63;
    int st = ptr[row], d = deg[row];
    float a0 = 0.f, a1 = 0.f;
    for (int j = 0; j < d; j++) {
        int2 e = ep[st + j];
        int c = e.x; float v = __int_as_float(e.y);
        const float* x = X + (size_t)c * F;
        const float* l = Lx + (size_t)c * F;
        a0 = fmaf(v, l[lane] * x[lane], a0);
        if (F > 64) { if (lane < F - 64) a1 = fmaf(v, l[lane + 64] * x[lane + 64], a1); }
    }
    float* o = outC + (size_t)i * F;
    o[lane] = a0;
    if (F > 64) { if (lane < F - 64) o[lane + 64] = a1; }
}

// ------------- Fused GNN linear: out = relu((Lx+X)@W + S2@Wi + b + bi) ----
template<int K, int M, int TPR>
__global__ __launch_bounds__(256) void gemm_fused(
    const float* __restrict__ Lx,
    const float* __restrict__ Xu, const float* __restrict__ Xi, int split,
    const float* __restrict__ S2,
    const float* __restrict__ W, const float* __restrict__ b,
    const float* __restrict__ Wi, const float* __restrict__ bi,
    float* __restrict__ out, int N)
{
    __shared__ float sW[K * M];
    __shared__ float sWi[K * M];
    for (int i = threadIdx.x; i < K * M; i += 256) {
        sW[i]  = W[i];
        sWi[i] = Wi[i];
    }
    __syncthreads();

    constexpr int RPB = 256 / TPR;
    constexpr int MT  = M / TPR;
    int r = blockIdx.x * RPB + (int)threadIdx.x / TPR;
    int mBase = ((int)threadIdx.x % TPR) * MT;
    if (r >= N) return;

    const float* xrow = (r < split) ? (Xu + (size_t)r * K)
                                    : (Xi + (size_t)(r - split) * K);
    const float* lrow = Lx + (size_t)r * K;
    const float* srow = S2 + (size_t)r * K;

    float acc[MT];
#pragma unroll
    for (int m = 0; m < MT; m++) acc[m] = 0.0f;

    static_assert(K % 4 == 0, "K must be multiple of 4");
    for (int k4 = 0; k4 < K; k4 += 4) {
        float4 lv = *(const float4*)(lrow + k4);
        float4 xv = *(const float4*)(xrow + k4);
        float4 sv = *(const float4*)(srow + k4);
        float a[4] = {lv.x + xv.x, lv.y + xv.y, lv.z + xv.z, lv.w + xv.w};
        float s[4] = {sv.x, sv.y, sv.z, sv.w};
#pragma unroll
        for (int kk = 0; kk < 4; kk++) {
            const float* wk  = &sW[(k4 + kk) * M + mBase];
            const float* wik = &sWi[(k4 + kk) * M + mBase];
#pragma unroll
            for (int m = 0; m < MT; m++)
                acc[m] = fmaf(a[kk], wk[m], fmaf(s[kk], wik[m], acc[m]));
        }
    }

    float* orow = out + (size_t)r * M + mBase;
#pragma unroll
    for (int m = 0; m < MT; m++)
        orow[m] = fmaxf(acc[m] + b[mBase + m] + bi[mBase + m], 0.0f);
}

// Layer-2 fused GEMM restricted to sampled rows; S2 and out are compact.
// K=80, M=50, TPR=2 -> 128 sel-entries/block, MT=25
__global__ __launch_bounds__(256) void gemm_fused2_sel(
    const float* __restrict__ Lx, const float* __restrict__ X,
    const float* __restrict__ S2c,
    const float* __restrict__ W, const float* __restrict__ b,
    const float* __restrict__ Wi, const float* __restrict__ bi,
    const int* __restrict__ userIdx, const int* __restrict__ itemIdx,
    float* __restrict__ outC)
{
    constexpr int K = 80, M = 50, TPR = 2, MT = M / TPR;
    __shared__ float sW[K * M];
    __shared__ float sWi[K * M];
    for (int i = threadIdx.x; i < K * M; i += 256) {
        sW[i]  = W[i];
        sWi[i] = Wi[i];
    }
    __syncthreads();

    int i = blockIdx.x * (256 / TPR) + (int)threadIdx.x / TPR;
    int mBase = ((int)threadIdx.x % TPR) * MT;
    if (i >= 2 * BATCH) return;
    int r = (i < BATCH) ? userIdx[i] : itemIdx[i - BATCH];

    const float* xrow = X + (size_t)r * K;
    const float* lrow = Lx + (size_t)r * K;
    const float* srow = S2c + (size_t)i * K;

    float acc[MT];
#pragma unroll
    for (int m = 0; m < MT; m++) acc[m] = 0.0f;

    for (int k4 = 0; k4 < K; k4 += 4) {
        float4 lv = *(const float4*)(lrow + k4);
        float4 xv = *(const float4*)(xrow + k4);
        float4 sv = *(const float4*)(srow + k4);
        float a[4] = {lv.x + xv.x, lv.y + xv.y, lv.z + xv.z, lv.w + xv.w};
        float s[4] = {sv.x, sv.y, sv.z, sv.w};
#pragma unroll
        for (int kk = 0; kk < 4; kk++) {
            const float* wk  = &sW[(k4 + kk) * M + mBase];
            const float* wik = &sWi[(k4 + kk) * M + mBase];
#pragma unroll
            for (int m = 0; m < MT; m++)
                acc[m] = fmaf(a[kk], wk[m], fmaf(s[kk], wik[m], acc[m]));
        }
    }

    float* orow = outC + (size_t)i * M + mBase;
#pragma unroll
    for (int m = 0; m < MT; m++)
        orow[m] = fmaxf(acc[m] + b[mBase + m] + bi[mBase + m], 0.0f);
}

// ------------- Plain MLP GEMM: out = (relu?)(A@W + b) ---------------------
template<int K, int M, int TPR, bool RELU>
__global__ __launch_bounds__(256) void mlp_gemm(
    const float* __restrict__ A,
    const float* __restrict__ W, const float* __restrict__ b,
    float* __restrict__ out, int N)
{
    __shared__ float sW[K * M];
    for (int i = threadIdx.x; i < K * M; i += 256) sW[i] = W[i];
    __syncthreads();

    constexpr int RPB = 256 / TPR;
    constexpr int MT  = M / TPR;
    int r = blockIdx.x * RPB + (int)threadIdx.x / TPR;
    int mBase = ((int)threadIdx.x % TPR) * MT;
    if (r >= N) return;

    const float* arow = A + (size_t)r * K;
    float acc[MT];
#pragma unroll
    for (int m = 0; m < MT; m++) acc[m] = 0.0f;

    for (int k = 0; k < K; k++) {
        float a = arow[k];
#pragma unroll
        for (int m = 0; m < MT; m++)
            acc[m] = fmaf(a, sW[k * M + mBase + m], acc[m]);
    }

    float* orow = out + (size_t)r * M + mBase;
#pragma unroll
    for (int m = 0; m < MT; m++) {
        float vv = acc[m] + b[mBase + m];
        orow[m] = RELU ? fmaxf(vv, 0.0f) : vv;
    }
}

// ------------- Gather final embeddings into [BATCH, 460] ------------------
// f2 is COMPACT: row bi of F2c = user bi, row BATCH+bi = item bi.
__global__ __launch_bounds__(128) void gather_embd(
    const int* __restrict__ userIdx, const int* __restrict__ itemIdx,
    const float* __restrict__ uE, const float* __restrict__ iE,
    const float* __restrict__ f1, const float* __restrict__ f2c,
    float* __restrict__ emb)
{
    int bi = blockIdx.x;
    int u  = userIdx[bi];
    int it = itemIdx[bi];
    float* orow = emb + (size_t)bi * 460;
    for (int c = threadIdx.x; c < 460; c += 128) {
        float val;
        if (c < 100) {
            val = (u < N_USERS) ? uE[(size_t)u * 100 + c]
                                : iE[(size_t)(u - N_USERS) * 100 + c];
        } else if (c < 180) {
            val = f1[(size_t)u * 80 + (c - 100)];
        } else if (c < 230) {
            val = f2c[(size_t)bi * 50 + (c - 180)];
        } else if (c < 330) {
            int cc = c - 230;
            val = (it < N_USERS) ? uE[(size_t)it * 100 + cc]
                                 : iE[(size_t)(it - N_USERS) * 100 + cc];
        } else if (c < 410) {
            val = f1[(size_t)it * 80 + (c - 330)];
        } else {
            val = f2c[(size_t)(BATCH + bi) * 50 + (c - 410)];
        }
        orow[c] = val;
    }
}

extern "C" void kernel_launch(void* const* d_in, const int* in_sizes, int n_in,
                              void* d_out, int out_size, void* d_ws, size_t ws_size,
                              hipStream_t stream) {
    const int*   userIdx = (const int*)d_in[0];
    const int*   itemIdx = (const int*)d_in[1];
    const int*   rows    = (const int*)d_in[2];
    const int*   cols    = (const int*)d_in[3];
    const float* vals    = (const float*)d_in[4];
    const float* uEmbd   = (const float*)d_in[5];
    const float* iEmbd   = (const float*)d_in[6];
    const float* w1      = (const float*)d_in[7];
    const float* b1      = (const float*)d_in[8];
    const float* wi1     = (const float*)d_in[9];
    const float* bi1     = (const float*)d_in[10];
    const float* w2      = (const float*)d_in[11];
    const float* b2      = (const float*)d_in[12];
    const float* wi2     = (const float*)d_in[13];
    const float* bi2     = (const float*)d_in[14];
    const float* t1w     = (const float*)d_in[15];
    const float* t1b     = (const float*)d_in[16];
    const float* t2w     = (const float*)d_in[17];
    const float* t2b     = (const float*)d_in[18];
    const float* t3w     = (const float*)d_in[19];
    const float* t3b     = (const float*)d_in[20];

    // ---- workspace layout (floats unless noted) ----
    float* ws = (float*)d_ws;
    float* B1   = ws;                         // 15,000,000  (150K x 100)
    float* B2   = B1  + 15000000;             // 15,000,000
    float* F1   = B2  + 15000000;             // 12,000,000  (150K x 80)
    float* F2c  = F1  + 12000000;             //    409,600  (8192 x 50)
    float* B2c  = F2c + 409600;               //    655,360  (8192 x 80)
    float* EMB  = B2c + 655360;               //  1,884,160  (4096 x 460)
    float* H1   = EMB + 1884160;              //    262,144
    float* H2   = H1  + 262144;               //    131,072
    int*   deg  = (int*)(H2 + 131072);        //    150,000 ints
    int*   ptr  = deg + 150000;               //    150,000
    int*   pos  = ptr + 150000;               //    150,000
    int*   bsum = pos + 150000;               //      1,024
    int*   epi  = bsum + 1024;                // pad to int2 alignment
    epi += ((uintptr_t)epi & 7) ? 1 : 0;
    int2*  ep   = (int2*)epi;                 //  1,500,000 int2 (12 MB)

    const int E = N_EDGES;
    dim3 blk(256);

    // ---- CSR build ----
    hipMemsetAsync(deg, 0, 150000 * sizeof(int), stream);
    hist_kernel<<<(E + 255) / 256, blk, 0, stream>>>(rows, deg, E);
    int nScanBlocks = (N_NODES + 255) / 256;            // 586
    scan_block<<<nScanBlocks, blk, 0, stream>>>(deg, ptr, bsum, N_NODES);
    scan_tops<<<1, dim3(1024), 0, stream>>>(bsum, nScanBlocks);
    scan_apply<<<nScanBlocks, blk, 0, stream>>>(ptr, bsum, pos, N_NODES);
    scatter_edges<<<(E + 255) / 256, blk, 0, stream>>>(rows, cols, vals, pos, ep, E);

    int rowGrid = (N_NODES + 3) / 4;       // 4 rows (waves) per block
    int selGrid = (2 * BATCH + 3) / 4;

    // ---- Layer 1 (F = 100) ----
    spmm_csr_x<100><<<rowGrid, blk, 0, stream>>>(
        ptr, deg, ep, uEmbd, iEmbd, N_USERS, B1, N_NODES);
    spmm_csr_inter_x<100><<<rowGrid, blk, 0, stream>>>(
        ptr, deg, ep, B1, uEmbd, iEmbd, N_USERS, B2, N_NODES);
    {   // F1 = relu((B1 + feats)@w1 + B2@wi1 + b1 + bi1)
        constexpr int TPR = 4;
        int grid = (N_NODES + (256 / TPR) - 1) / (256 / TPR);
        gemm_fused<100, 80, TPR><<<grid, blk, 0, stream>>>(
            B1, uEmbd, iEmbd, N_USERS, B2, w1, b1, wi1, bi1, F1, N_NODES);
    }

    // ---- Layer 2 (F = 80) ----
    spmm_csr_x<80><<<rowGrid, blk, 0, stream>>>(
        ptr, deg, ep, F1, F1, N_NODES, B1, N_NODES);
    spmm_csr_inter_sel<80><<<selGrid, blk, 0, stream>>>(
        ptr, deg, ep, B1, F1, userIdx, itemIdx, B2c);
    {
        int grid = (2 * BATCH + 127) / 128;
        gemm_fused2_sel<<<grid, blk, 0, stream>>>(
            B1, F1, B2c, w2, b2, wi2, bi2, userIdx, itemIdx, F2c);
    }

    // ---- Gather + MLP ----
    gather_embd<<<BATCH, dim3(128), 0, stream>>>(
        userIdx, itemIdx, uEmbd, iEmbd, F1, F2c, EMB);
    {
        constexpr int TPR = 8;
        int grid = (BATCH + (256 / TPR) - 1) / (256 / TPR);
        mlp_gemm<460, 64, TPR, true><<<grid, blk, 0, stream>>>(
            EMB, t1w, t1b, H1, BATCH);
    }
    {
        constexpr int TPR = 4;
        int grid = (BATCH + (256 / TPR) - 1) / (256 / TPR);
        mlp_gemm<64, 32, TPR, false><<<grid, blk, 0, stream>>>(
            H1, t2w, t2b, H2, BATCH);
    }
    {
        constexpr int TPR = 1;
        int grid = (BATCH + 255) / 256;
        mlp_gemm<32, 1, TPR, false><<<grid, blk, 0, stream>>>(
            H2, t3w, t3b, (float*)d_out, BATCH);
    }
}

// Round 3
// 752.435 us; speedup vs baseline: 3.3563x; 1.2706x over previous
//
#include <hip/hip_runtime.h>

typedef unsigned int uint;

#define N_USERS 100000
#define N_ITEMS 50000
#define N_NODES 150000
#define N_EDGES 1500000
#define BATCH 4096

__device__ __forceinline__ uint pack_bf16x2(float a, float b) {
    uint ua = __float_as_uint(a);
    uint ub = __float_as_uint(b);
    ua = (ua + 0x7FFFu + ((ua >> 16) & 1u)) >> 16;
    ub = (ub + 0x7FFFu + ((ub >> 16) & 1u)) >> 16;
    return ua | (ub << 16);
}
__device__ __forceinline__ float bf_lo(uint u) { return __uint_as_float(u << 16); }
__device__ __forceinline__ float bf_hi(uint u) { return __uint_as_float(u & 0xFFFF0000u); }

// ======================= bf16 feature cast (concat u,i) =======================
__global__ __launch_bounds__(256) void cast_feats(
    const float* __restrict__ uE, const float* __restrict__ iE,
    uint* __restrict__ Xb)
{
    int g = blockIdx.x * 256 + threadIdx.x;       // one uint = 2 features
    if (g >= N_NODES * 50) return;                // 7.5M
    int e0 = g * 2;
    float a, b;
    if (e0 < N_USERS * 100) { a = uE[e0]; b = uE[e0 + 1]; }
    else { a = iE[e0 - N_USERS * 100]; b = iE[e0 - N_USERS * 100 + 1]; }
    Xb[g] = pack_bf16x2(a, b);
}

// ======================= CSR construction =======================
__global__ __launch_bounds__(256) void hist_kernel(
    const int* __restrict__ rows, int* __restrict__ deg, int E)
{
    int e = blockIdx.x * 256 + threadIdx.x;
    if (e < E) atomicAdd(&deg[rows[e]], 1);
}

__global__ __launch_bounds__(256) void scan_block(
    const int* __restrict__ deg, int* __restrict__ ptr,
    int* __restrict__ bsum, int n)
{
    __shared__ int s[256];
    int t = threadIdx.x;
    int i = blockIdx.x * 256 + t;
    int v = (i < n) ? deg[i] : 0;
    s[t] = v; __syncthreads();
    for (int off = 1; off < 256; off <<= 1) {
        int x = (t >= off) ? s[t - off] : 0;
        __syncthreads();
        s[t] += x;
        __syncthreads();
    }
    if (i < n) ptr[i] = s[t] - v;
    if (t == 255) bsum[blockIdx.x] = s[255];
}

__global__ __launch_bounds__(1024) void scan_tops(int* __restrict__ bsum, int nb)
{
    __shared__ int s[1024];
    int t = threadIdx.x;
    int v = (t < nb) ? bsum[t] : 0;
    s[t] = v; __syncthreads();
    for (int off = 1; off < 1024; off <<= 1) {
        int x = (t >= off) ? s[t - off] : 0;
        __syncthreads();
        s[t] += x;
        __syncthreads();
    }
    if (t < nb) bsum[t] = s[t] - v;
}

__global__ __launch_bounds__(256) void scan_apply(
    int* __restrict__ ptr, const int* __restrict__ bsum,
    int* __restrict__ pos, int n)
{
    int i = blockIdx.x * 256 + threadIdx.x;
    if (i < n) {
        int p = ptr[i] + bsum[i >> 8];
        ptr[i] = p;
        pos[i] = p;
    }
}

__global__ __launch_bounds__(256) void scatter_edges(
    const int* __restrict__ rows, const int* __restrict__ cols,
    const float* __restrict__ vals, int* __restrict__ pos,
    int2* __restrict__ ep, int E)
{
    int e = blockIdx.x * 256 + threadIdx.x;
    if (e < E) {
        int r = rows[e];
        int p = atomicAdd(&pos[r], 1);
        ep[p] = make_int2(cols[e], __float_as_int(vals[e]));
    }
}

// ======================= SpMM kernels (bf16 gather) =======================
// One 64-lane wave per row; lane j handles features {2j, 2j+1} (P = F/2 lanes).

// Pass 1: B1 = L@X (fp32 out) + epilogue INTERb = bf16(B1 .* X)
template<int F>
__global__ __launch_bounds__(256) void spmm_bf_epi(
    const int* __restrict__ ptr_, const int* __restrict__ deg_,
    const int2* __restrict__ ep, const uint* __restrict__ Xb,
    float* __restrict__ out, uint* __restrict__ INTb, int N)
{
    constexpr int P = F / 2;
    int row = blockIdx.x * 4 + ((int)threadIdx.x >> 6);
    if (row >= N) return;
    int lane = threadIdx.x & 63;
    int st = ptr_[row], d = deg_[row];
    float ax = 0.f, ay = 0.f;
    int2 e = (d > 0) ? ep[st] : make_int2(0, 0);
    for (int j = 0; j < d; j++) {
        int c = e.x; float v = __int_as_float(e.y);
        if (j + 1 < d) e = ep[st + j + 1];
        uint bits = (lane < P) ? Xb[(size_t)c * P + lane] : 0u;
        ax = fmaf(v, bf_lo(bits), ax);
        ay = fmaf(v, bf_hi(bits), ay);
    }
    if (lane < P) {
        ((float2*)(out + (size_t)row * F))[lane] = make_float2(ax, ay);
        uint xb = Xb[(size_t)row * P + lane];
        INTb[(size_t)row * P + lane] = pack_bf16x2(ax * bf_lo(xb), ay * bf_hi(xb));
    }
}

// Pass 2/3: out = L @ bf16src (fp32 out)
template<int F>
__global__ __launch_bounds__(256) void spmm_bf(
    const int* __restrict__ ptr_, const int* __restrict__ deg_,
    const int2* __restrict__ ep, const uint* __restrict__ Xb,
    float* __restrict__ out, int N)
{
    constexpr int P = F / 2;
    int row = blockIdx.x * 4 + ((int)threadIdx.x >> 6);
    if (row >= N) return;
    int lane = threadIdx.x & 63;
    int st = ptr_[row], d = deg_[row];
    float ax = 0.f, ay = 0.f;
    int2 e = (d > 0) ? ep[st] : make_int2(0, 0);
    for (int j = 0; j < d; j++) {
        int c = e.x; float v = __int_as_float(e.y);
        if (j + 1 < d) e = ep[st + j + 1];
        uint bits = (lane < P) ? Xb[(size_t)c * P + lane] : 0u;
        ax = fmaf(v, bf_lo(bits), ax);
        ay = fmaf(v, bf_hi(bits), ay);
    }
    if (lane < P)
        ((float2*)(out + (size_t)row * F))[lane] = make_float2(ax, ay);
}

// Pass 4 (selected rows): outC[i] = sum_e v * (Lx[c] .* F1[c]) ; F1 via bf16
__global__ __launch_bounds__(256) void spmm_sel(
    const int* __restrict__ ptr_, const int* __restrict__ deg_,
    const int2* __restrict__ ep,
    const float* __restrict__ Lx, const uint* __restrict__ F1b,
    const int* __restrict__ userIdx, const int* __restrict__ itemIdx,
    float* __restrict__ outC)
{
    constexpr int P = 40;   // F = 80
    int i = blockIdx.x * 4 + ((int)threadIdx.x >> 6);
    if (i >= 2 * BATCH) return;
    int row = (i < BATCH) ? userIdx[i] : itemIdx[i - BATCH];
    int lane = threadIdx.x & 63;
    int st = ptr_[row], d = deg_[row];
    float ax = 0.f, ay = 0.f;
    int2 e = (d > 0) ? ep[st] : make_int2(0, 0);
    for (int j = 0; j < d; j++) {
        int c = e.x; float v = __int_as_float(e.y);
        if (j + 1 < d) e = ep[st + j + 1];
        float2 l = make_float2(0.f, 0.f);
        uint bits = 0u;
        if (lane < P) {
            l = ((const float2*)(Lx + (size_t)c * 80))[lane];
            bits = F1b[(size_t)c * P + lane];
        }
        ax = fmaf(v, l.x * bf_lo(bits), ax);
        ay = fmaf(v, l.y * bf_hi(bits), ay);
    }
    if (lane < P)
        ((float2*)(outC + (size_t)i * 80))[lane] = make_float2(ax, ay);
}

// ------------- Layer-1 fused linear + bf16 epilogue -----------------------
// out = relu((Lx+X)@W + S2@Wi + b + bi); also writes bf16 copy F1b
template<int K, int M, int TPR>
__global__ __launch_bounds__(256) void gemm_fused1(
    const float* __restrict__ Lx,
    const float* __restrict__ Xu, const float* __restrict__ Xi, int split,
    const float* __restrict__ S2,
    const float* __restrict__ W, const float* __restrict__ b,
    const float* __restrict__ Wi, const float* __restrict__ bi,
    float* __restrict__ out, uint* __restrict__ outB, int N)
{
    __shared__ float sW[K * M];
    __shared__ float sWi[K * M];
    for (int i = threadIdx.x; i < K * M; i += 256) {
        sW[i]  = W[i];
        sWi[i] = Wi[i];
    }
    __syncthreads();

    constexpr int RPB = 256 / TPR;
    constexpr int MT  = M / TPR;
    static_assert(MT % 2 == 0, "");
    int r = blockIdx.x * RPB + (int)threadIdx.x / TPR;
    int mBase = ((int)threadIdx.x % TPR) * MT;
    if (r >= N) return;

    const float* xrow = (r < split) ? (Xu + (size_t)r * K)
                                    : (Xi + (size_t)(r - split) * K);
    const float* lrow = Lx + (size_t)r * K;
    const float* srow = S2 + (size_t)r * K;

    float acc[MT];
#pragma unroll
    for (int m = 0; m < MT; m++) acc[m] = 0.0f;

    for (int k4 = 0; k4 < K; k4 += 4) {
        float4 lv = *(const float4*)(lrow + k4);
        float4 xv = *(const float4*)(xrow + k4);
        float4 sv = *(const float4*)(srow + k4);
        float a[4] = {lv.x + xv.x, lv.y + xv.y, lv.z + xv.z, lv.w + xv.w};
        float s[4] = {sv.x, sv.y, sv.z, sv.w};
#pragma unroll
        for (int kk = 0; kk < 4; kk++) {
            const float* wk  = &sW[(k4 + kk) * M + mBase];
            const float* wik = &sWi[(k4 + kk) * M + mBase];
#pragma unroll
            for (int m = 0; m < MT; m++)
                acc[m] = fmaf(a[kk], wk[m], fmaf(s[kk], wik[m], acc[m]));
        }
    }

    float vv[MT];
#pragma unroll
    for (int m = 0; m < MT; m++)
        vv[m] = fmaxf(acc[m] + b[mBase + m] + bi[mBase + m], 0.0f);

    float* orow = out + (size_t)r * M + mBase;
#pragma unroll
    for (int m = 0; m < MT; m++) orow[m] = vv[m];

    uint* brow = outB + (size_t)r * (M / 2) + (mBase >> 1);
#pragma unroll
    for (int m = 0; m < MT; m += 2)
        brow[m >> 1] = pack_bf16x2(vv[m], vv[m + 1]);
}

// Layer-2 fused GEMM restricted to sampled rows; S2 and out are compact.
__global__ __launch_bounds__(256) void gemm_fused2_sel(
    const float* __restrict__ Lx, const float* __restrict__ X,
    const float* __restrict__ S2c,
    const float* __restrict__ W, const float* __restrict__ b,
    const float* __restrict__ Wi, const float* __restrict__ bi,
    const int* __restrict__ userIdx, const int* __restrict__ itemIdx,
    float* __restrict__ outC)
{
    constexpr int K = 80, M = 50, TPR = 2, MT = M / TPR;
    __shared__ float sW[K * M];
    __shared__ float sWi[K * M];
    for (int i = threadIdx.x; i < K * M; i += 256) {
        sW[i]  = W[i];
        sWi[i] = Wi[i];
    }
    __syncthreads();

    int i = blockIdx.x * (256 / TPR) + (int)threadIdx.x / TPR;
    int mBase = ((int)threadIdx.x % TPR) * MT;
    if (i >= 2 * BATCH) return;
    int r = (i < BATCH) ? userIdx[i] : itemIdx[i - BATCH];

    const float* xrow = X + (size_t)r * K;
    const float* lrow = Lx + (size_t)r * K;
    const float* srow = S2c + (size_t)i * K;

    float acc[MT];
#pragma unroll
    for (int m = 0; m < MT; m++) acc[m] = 0.0f;

    for (int k4 = 0; k4 < K; k4 += 4) {
        float4 lv = *(const float4*)(lrow + k4);
        float4 xv = *(const float4*)(xrow + k4);
        float4 sv = *(const float4*)(srow + k4);
        float a[4] = {lv.x + xv.x, lv.y + xv.y, lv.z + xv.z, lv.w + xv.w};
        float s[4] = {sv.x, sv.y, sv.z, sv.w};
#pragma unroll
        for (int kk = 0; kk < 4; kk++) {
            const float* wk  = &sW[(k4 + kk) * M + mBase];
            const float* wik = &sWi[(k4 + kk) * M + mBase];
#pragma unroll
            for (int m = 0; m < MT; m++)
                acc[m] = fmaf(a[kk], wk[m], fmaf(s[kk], wik[m], acc[m]));
        }
    }

    float* orow = outC + (size_t)i * M + mBase;
#pragma unroll
    for (int m = 0; m < MT; m++)
        orow[m] = fmaxf(acc[m] + b[mBase + m] + bi[mBase + m], 0.0f);
}

// ------------- Plain MLP GEMM ---------------------------------------------
template<int K, int M, int TPR, bool RELU>
__global__ __launch_bounds__(256) void mlp_gemm(
    const float* __restrict__ A,
    const float* __restrict__ W, const float* __restrict__ b,
    float* __restrict__ out, int N)
{
    __shared__ float sW[K * M];
    for (int i = threadIdx.x; i < K * M; i += 256) sW[i] = W[i];
    __syncthreads();

    constexpr int RPB = 256 / TPR;
    constexpr int MT  = M / TPR;
    int r = blockIdx.x * RPB + (int)threadIdx.x / TPR;
    int mBase = ((int)threadIdx.x % TPR) * MT;
    if (r >= N) return;

    const float* arow = A + (size_t)r * K;
    float acc[MT];
#pragma unroll
    for (int m = 0; m < MT; m++) acc[m] = 0.0f;

    for (int k = 0; k < K; k++) {
        float a = arow[k];
#pragma unroll
        for (int m = 0; m < MT; m++)
            acc[m] = fmaf(a, sW[k * M + mBase + m], acc[m]);
    }

    float* orow = out + (size_t)r * M + mBase;
#pragma unroll
    for (int m = 0; m < MT; m++) {
        float vv = acc[m] + b[mBase + m];
        orow[m] = RELU ? fmaxf(vv, 0.0f) : vv;
    }
}

// ------------- Gather final embeddings into [BATCH, 460] ------------------
__global__ __launch_bounds__(128) void gather_embd(
    const int* __restrict__ userIdx, const int* __restrict__ itemIdx,
    const float* __restrict__ uE, const float* __restrict__ iE,
    const float* __restrict__ f1, const float* __restrict__ f2c,
    float* __restrict__ emb)
{
    int bi = blockIdx.x;
    int u  = userIdx[bi];
    int it = itemIdx[bi];
    float* orow = emb + (size_t)bi * 460;
    for (int c = threadIdx.x; c < 460; c += 128) {
        float val;
        if (c < 100) {
            val = (u < N_USERS) ? uE[(size_t)u * 100 + c]
                                : iE[(size_t)(u - N_USERS) * 100 + c];
        } else if (c < 180) {
            val = f1[(size_t)u * 80 + (c - 100)];
        } else if (c < 230) {
            val = f2c[(size_t)bi * 50 + (c - 180)];
        } else if (c < 330) {
            int cc = c - 230;
            val = (it < N_USERS) ? uE[(size_t)it * 100 + cc]
                                 : iE[(size_t)(it - N_USERS) * 100 + cc];
        } else if (c < 410) {
            val = f1[(size_t)it * 80 + (c - 330)];
        } else {
            val = f2c[(size_t)(BATCH + bi) * 50 + (c - 410)];
        }
        orow[c] = val;
    }
}

extern "C" void kernel_launch(void* const* d_in, const int* in_sizes, int n_in,
                              void* d_out, int out_size, void* d_ws, size_t ws_size,
                              hipStream_t stream) {
    const int*   userIdx = (const int*)d_in[0];
    const int*   itemIdx = (const int*)d_in[1];
    const int*   rows    = (const int*)d_in[2];
    const int*   cols    = (const int*)d_in[3];
    const float* vals    = (const float*)d_in[4];
    const float* uEmbd   = (const float*)d_in[5];
    const float* iEmbd   = (const float*)d_in[6];
    const float* w1      = (const float*)d_in[7];
    const float* b1      = (const float*)d_in[8];
    const float* wi1     = (const float*)d_in[9];
    const float* bi1     = (const float*)d_in[10];
    const float* w2      = (const float*)d_in[11];
    const float* b2      = (const float*)d_in[12];
    const float* wi2     = (const float*)d_in[13];
    const float* bi2     = (const float*)d_in[14];
    const float* t1w     = (const float*)d_in[15];
    const float* t1b     = (const float*)d_in[16];
    const float* t2w     = (const float*)d_in[17];
    const float* t2b     = (const float*)d_in[18];
    const float* t3w     = (const float*)d_in[19];
    const float* t3b     = (const float*)d_in[20];

    // ---- workspace layout (4-byte units), with aliasing ----
    float* ws = (float*)d_ws;
    float* B1   = ws;                          // 15,000,000 (L@X layer1; reused as L@F1 layer2)
    float* B2   = ws + 15000000;               // 15,000,000 (pass-2 out; tail bufs alias after gemm1)
    float* F1   = ws + 30000000;               // 12,000,000 fp32 (alias: first 7.5M = INTERbf before gemm1)
    uint*  INTb = (uint*)F1;                   //  7,500,000 uints (dead after pass 2)
    uint*  Xb   = (uint*)(ws + 42000000);      //  7,500,000 uints (dead after pass 1; F1b aliases)
    uint*  F1b  = Xb;                          //  6,000,000 uints (written by gemm1)
    // tail buffers inside B2 region (B2 dead after gemm1):
    float* F2c  = B2;                          //   409,600
    float* B2c  = B2 + 409600;                 //   655,360
    float* EMB  = B2 + 1064960;                // 1,884,160
    float* H1   = B2 + 2949120;                //   262,144
    float* H2   = B2 + 3211264;                //   131,072
    int*   deg  = (int*)(ws + 49500000);       //   150,000
    int*   ptr  = deg + 150000;
    int*   pos  = ptr + 150000;
    int*   bsum = pos + 150000;                //     1,024
    int2*  ep   = (int2*)(bsum + 1024);        // 1,500,000 int2 (12 MB); offset is 8B-aligned

    const int E = N_EDGES;
    dim3 blk(256);

    // ---- bf16 feature cast (independent of CSR build) ----
    cast_feats<<<(N_NODES * 50 + 255) / 256, blk, 0, stream>>>(uEmbd, iEmbd, Xb);

    // ---- CSR build ----
    hipMemsetAsync(deg, 0, 150000 * sizeof(int), stream);
    hist_kernel<<<(E + 255) / 256, blk, 0, stream>>>(rows, deg, E);
    int nScanBlocks = (N_NODES + 255) / 256;            // 586
    scan_block<<<nScanBlocks, blk, 0, stream>>>(deg, ptr, bsum, N_NODES);
    scan_tops<<<1, dim3(1024), 0, stream>>>(bsum, nScanBlocks);
    scan_apply<<<nScanBlocks, blk, 0, stream>>>(ptr, bsum, pos, N_NODES);
    scatter_edges<<<(E + 255) / 256, blk, 0, stream>>>(rows, cols, vals, pos, ep, E);

    int rowGrid = (N_NODES + 3) / 4;
    int selGrid = (2 * BATCH + 3) / 4;

    // ---- Layer 1 (F = 100) ----
    spmm_bf_epi<100><<<rowGrid, blk, 0, stream>>>(
        ptr, deg, ep, Xb, B1, INTb, N_NODES);
    spmm_bf<100><<<rowGrid, blk, 0, stream>>>(
        ptr, deg, ep, INTb, B2, N_NODES);
    {
        constexpr int TPR = 4;
        int grid = (N_NODES + (256 / TPR) - 1) / (256 / TPR);
        gemm_fused1<100, 80, TPR><<<grid, blk, 0, stream>>>(
            B1, uEmbd, iEmbd, N_USERS, B2, w1, b1, wi1, bi1, F1, F1b, N_NODES);
    }

    // ---- Layer 2 (F = 80) ----
    spmm_bf<80><<<rowGrid, blk, 0, stream>>>(
        ptr, deg, ep, F1b, B1, N_NODES);
    spmm_sel<<<selGrid, blk, 0, stream>>>(
        ptr, deg, ep, B1, F1b, userIdx, itemIdx, B2c);
    {
        int grid = (2 * BATCH + 127) / 128;
        gemm_fused2_sel<<<grid, blk, 0, stream>>>(
            B1, F1, B2c, w2, b2, wi2, bi2, userIdx, itemIdx, F2c);
    }

    // ---- Gather + MLP ----
    gather_embd<<<BATCH, dim3(128), 0, stream>>>(
        userIdx, itemIdx, uEmbd, iEmbd, F1, F2c, EMB);
    {
        constexpr int TPR = 8;
        int grid = (BATCH + (256 / TPR) - 1) / (256 / TPR);
        mlp_gemm<460, 64, TPR, true><<<grid, blk, 0, stream>>>(
            EMB, t1w, t1b, H1, BATCH);
    }
    {
        constexpr int TPR = 4;
        int grid = (BATCH + (256 / TPR) - 1) / (256 / TPR);
        mlp_gemm<64, 32, TPR, false><<<grid, blk, 0, stream>>>(
            H1, t2w, t2b, H2, BATCH);
    }
    {
        constexpr int TPR = 1;
        int grid = (BATCH + 255) / 256;
        mlp_gemm<32, 1, TPR, false><<<grid, blk, 0, stream>>>(
            H2, t3w, t3b, (float*)d_out, BATCH);
    }
}

// Round 4
// 723.808 us; speedup vs baseline: 3.4890x; 1.0396x over previous
//
#include <hip/hip_runtime.h>

typedef unsigned int uint;

#define N_USERS 100000
#define N_ITEMS 50000
#define N_NODES 150000
#define N_EDGES 1500000
#define BATCH 4096

__device__ __forceinline__ uint pack_bf16x2(float a, float b) {
    uint ua = __float_as_uint(a);
    uint ub = __float_as_uint(b);
    ua = (ua + 0x7FFFu + ((ua >> 16) & 1u)) >> 16;
    ub = (ub + 0x7FFFu + ((ub >> 16) & 1u)) >> 16;
    return ua | (ub << 16);
}
__device__ __forceinline__ float bf_lo(uint u) { return __uint_as_float(u << 16); }
__device__ __forceinline__ float bf_hi(uint u) { return __uint_as_float(u & 0xFFFF0000u); }

// ======================= bf16 feature cast (concat u,i) =======================
__global__ __launch_bounds__(256) void cast_feats(
    const float* __restrict__ uE, const float* __restrict__ iE,
    uint* __restrict__ Xb)
{
    int g = blockIdx.x * 256 + threadIdx.x;       // one uint = 2 features
    if (g >= N_NODES * 50) return;                // 7.5M
    int e0 = g * 2;
    float a, b;
    if (e0 < N_USERS * 100) { a = uE[e0]; b = uE[e0 + 1]; }
    else { a = iE[e0 - N_USERS * 100]; b = iE[e0 - N_USERS * 100 + 1]; }
    Xb[g] = pack_bf16x2(a, b);
}

// ======================= CSR construction =======================
__global__ __launch_bounds__(256) void hist_kernel(
    const int* __restrict__ rows, int* __restrict__ deg, int E)
{
    int e = blockIdx.x * 256 + threadIdx.x;
    if (e < E) atomicAdd(&deg[rows[e]], 1);
}

__global__ __launch_bounds__(256) void scan_block(
    const int* __restrict__ deg, int* __restrict__ ptr,
    int* __restrict__ bsum, int n)
{
    __shared__ int s[256];
    int t = threadIdx.x;
    int i = blockIdx.x * 256 + t;
    int v = (i < n) ? deg[i] : 0;
    s[t] = v; __syncthreads();
    for (int off = 1; off < 256; off <<= 1) {
        int x = (t >= off) ? s[t - off] : 0;
        __syncthreads();
        s[t] += x;
        __syncthreads();
    }
    if (i < n) ptr[i] = s[t] - v;
    if (t == 255) bsum[blockIdx.x] = s[255];
}

__global__ __launch_bounds__(1024) void scan_tops(int* __restrict__ bsum, int nb)
{
    __shared__ int s[1024];
    int t = threadIdx.x;
    int v = (t < nb) ? bsum[t] : 0;
    s[t] = v; __syncthreads();
    for (int off = 1; off < 1024; off <<= 1) {
        int x = (t >= off) ? s[t - off] : 0;
        __syncthreads();
        s[t] += x;
        __syncthreads();
    }
    if (t < nb) bsum[t] = s[t] - v;
}

__global__ __launch_bounds__(256) void scan_apply(
    int* __restrict__ ptr, const int* __restrict__ bsum,
    int* __restrict__ pos, int n)
{
    int i = blockIdx.x * 256 + threadIdx.x;
    if (i < n) {
        int p = ptr[i] + bsum[i >> 8];
        ptr[i] = p;
        pos[i] = p;
    }
}

__global__ __launch_bounds__(256) void scatter_edges(
    const int* __restrict__ rows, const int* __restrict__ cols,
    const float* __restrict__ vals, int* __restrict__ pos,
    int2* __restrict__ ep, int E)
{
    int e = blockIdx.x * 256 + threadIdx.x;
    if (e < E) {
        int r = rows[e];
        int p = atomicAdd(&pos[r], 1);
        ep[p] = make_int2(cols[e], __float_as_int(vals[e]));
    }
}

// ============== needed-row marking for layer-2 pass 3 =====================
// needed = selected rows  ∪  columns of selected rows' edges
__global__ __launch_bounds__(256) void mark_needed(
    const int* __restrict__ userIdx, const int* __restrict__ itemIdx,
    const int* __restrict__ ptr_, const int* __restrict__ deg_,
    const int2* __restrict__ ep, int* __restrict__ flag)
{
    int i = blockIdx.x * 4 + ((int)threadIdx.x >> 6);
    if (i >= 2 * BATCH) return;
    int lane = threadIdx.x & 63;
    int row = (i < BATCH) ? userIdx[i] : itemIdx[i - BATCH];
    if (lane == 0) flag[row] = 1;
    int st = ptr_[row], d = deg_[row];
    for (int j = lane; j < d; j += 64)
        flag[ep[st + j].x] = 1;
}

__global__ __launch_bounds__(256) void compact_list(
    const int* __restrict__ flag, const int* __restrict__ fpre,
    const int* __restrict__ bsum, int* __restrict__ list,
    int* __restrict__ count, int n)
{
    int i = blockIdx.x * 256 + threadIdx.x;
    if (i < n) {
        int base = fpre[i] + bsum[i >> 8];
        if (flag[i]) list[base] = i;
        if (i == n - 1) *count = base + flag[i];
    }
}

// ======================= SpMM kernels (bf16 gather) =======================
// One 64-lane wave per row; lane j handles features {2j, 2j+1} (P = F/2).

// Pass 1: B1 = L@X (fp32 out) + epilogue INTERb = bf16(B1 .* X)
template<int F>
__global__ __launch_bounds__(256) void spmm_bf_epi(
    const int* __restrict__ ptr_, const int* __restrict__ deg_,
    const int2* __restrict__ ep, const uint* __restrict__ Xb,
    float* __restrict__ out, uint* __restrict__ INTb, int N)
{
    constexpr int P = F / 2;
    int row = blockIdx.x * 4 + ((int)threadIdx.x >> 6);
    if (row >= N) return;
    int lane = threadIdx.x & 63;
    int st = ptr_[row], d = deg_[row];
    float ax = 0.f, ay = 0.f;
    int2 e = (d > 0) ? ep[st] : make_int2(0, 0);
    for (int j = 0; j < d; j++) {
        int c = e.x; float v = __int_as_float(e.y);
        if (j + 1 < d) e = ep[st + j + 1];
        uint bits = (lane < P) ? Xb[(size_t)c * P + lane] : 0u;
        ax = fmaf(v, bf_lo(bits), ax);
        ay = fmaf(v, bf_hi(bits), ay);
    }
    if (lane < P) {
        ((float2*)(out + (size_t)row * F))[lane] = make_float2(ax, ay);
        uint xb = Xb[(size_t)row * P + lane];
        INTb[(size_t)row * P + lane] = pack_bf16x2(ax * bf_lo(xb), ay * bf_hi(xb));
    }
}

// Pass 2: out = L @ bf16src (fp32 out), all rows
template<int F>
__global__ __launch_bounds__(256) void spmm_bf(
    const int* __restrict__ ptr_, const int* __restrict__ deg_,
    const int2* __restrict__ ep, const uint* __restrict__ Xb,
    float* __restrict__ out, int N)
{
    constexpr int P = F / 2;
    int row = blockIdx.x * 4 + ((int)threadIdx.x >> 6);
    if (row >= N) return;
    int lane = threadIdx.x & 63;
    int st = ptr_[row], d = deg_[row];
    float ax = 0.f, ay = 0.f;
    int2 e = (d > 0) ? ep[st] : make_int2(0, 0);
    for (int j = 0; j < d; j++) {
        int c = e.x; float v = __int_as_float(e.y);
        if (j + 1 < d) e = ep[st + j + 1];
        uint bits = (lane < P) ? Xb[(size_t)c * P + lane] : 0u;
        ax = fmaf(v, bf_lo(bits), ax);
        ay = fmaf(v, bf_hi(bits), ay);
    }
    if (lane < P)
        ((float2*)(out + (size_t)row * F))[lane] = make_float2(ax, ay);
}

// Pass 3: like spmm_bf<80> but only over compacted needed-row list
__global__ __launch_bounds__(256) void spmm_bf_list(
    const int* __restrict__ list, const int* __restrict__ count,
    const int* __restrict__ ptr_, const int* __restrict__ deg_,
    const int2* __restrict__ ep, const uint* __restrict__ Xb,
    float* __restrict__ out)
{
    constexpr int P = 40;   // F = 80
    int idx = blockIdx.x * 4 + ((int)threadIdx.x >> 6);
    if (idx >= *count) return;
    int row = list[idx];
    int lane = threadIdx.x & 63;
    int st = ptr_[row], d = deg_[row];
    float ax = 0.f, ay = 0.f;
    int2 e = (d > 0) ? ep[st] : make_int2(0, 0);
    for (int j = 0; j < d; j++) {
        int c = e.x; float v = __int_as_float(e.y);
        if (j + 1 < d) e = ep[st + j + 1];
        uint bits = (lane < P) ? Xb[(size_t)c * P + lane] : 0u;
        ax = fmaf(v, bf_lo(bits), ax);
        ay = fmaf(v, bf_hi(bits), ay);
    }
    if (lane < P)
        ((float2*)(out + (size_t)row * 80))[lane] = make_float2(ax, ay);
}

// Pass 4 (selected rows): outC[i] = sum_e v * (Lx[c] .* F1[c]) ; F1 via bf16
__global__ __launch_bounds__(256) void spmm_sel(
    const int* __restrict__ ptr_, const int* __restrict__ deg_,
    const int2* __restrict__ ep,
    const float* __restrict__ Lx, const uint* __restrict__ F1b,
    const int* __restrict__ userIdx, const int* __restrict__ itemIdx,
    float* __restrict__ outC)
{
    constexpr int P = 40;   // F = 80
    int i = blockIdx.x * 4 + ((int)threadIdx.x >> 6);
    if (i >= 2 * BATCH) return;
    int row = (i < BATCH) ? userIdx[i] : itemIdx[i - BATCH];
    int lane = threadIdx.x & 63;
    int st = ptr_[row], d = deg_[row];
    float ax = 0.f, ay = 0.f;
    int2 e = (d > 0) ? ep[st] : make_int2(0, 0);
    for (int j = 0; j < d; j++) {
        int c = e.x; float v = __int_as_float(e.y);
        if (j + 1 < d) e = ep[st + j + 1];
        float2 l = make_float2(0.f, 0.f);
        uint bits = 0u;
        if (lane < P) {
            l = ((const float2*)(Lx + (size_t)c * 80))[lane];
            bits = F1b[(size_t)c * P + lane];
        }
        ax = fmaf(v, l.x * bf_lo(bits), ax);
        ay = fmaf(v, l.y * bf_hi(bits), ay);
    }
    if (lane < P)
        ((float2*)(outC + (size_t)i * 80))[lane] = make_float2(ax, ay);
}

// ------------- Layer-1 fused linear + bf16 epilogue -----------------------
// 1024-thread blocks: 16 waves = full VGPR-capped CU occupancy despite 64KB LDS.
template<int K, int M, int TPR>
__global__ __launch_bounds__(1024) void gemm_fused1(
    const float* __restrict__ Lx,
    const float* __restrict__ Xu, const float* __restrict__ Xi, int split,
    const float* __restrict__ S2,
    const float* __restrict__ W, const float* __restrict__ b,
    const float* __restrict__ Wi, const float* __restrict__ bi,
    float* __restrict__ out, uint* __restrict__ outB, int N)
{
    __shared__ float sW[K * M];
    __shared__ float sWi[K * M];
    for (int i = threadIdx.x; i < K * M; i += 1024) {
        sW[i]  = W[i];
        sWi[i] = Wi[i];
    }
    __syncthreads();

    constexpr int RPB = 1024 / TPR;
    constexpr int MT  = M / TPR;
    static_assert(MT % 2 == 0, "");
    int r = blockIdx.x * RPB + (int)threadIdx.x / TPR;
    int mBase = ((int)threadIdx.x % TPR) * MT;
    if (r >= N) return;

    const float* xrow = (r < split) ? (Xu + (size_t)r * K)
                                    : (Xi + (size_t)(r - split) * K);
    const float* lrow = Lx + (size_t)r * K;
    const float* srow = S2 + (size_t)r * K;

    float acc[MT];
#pragma unroll
    for (int m = 0; m < MT; m++) acc[m] = 0.0f;

    for (int k4 = 0; k4 < K; k4 += 4) {
        float4 lv = *(const float4*)(lrow + k4);
        float4 xv = *(const float4*)(xrow + k4);
        float4 sv = *(const float4*)(srow + k4);
        float a[4] = {lv.x + xv.x, lv.y + xv.y, lv.z + xv.z, lv.w + xv.w};
        float s[4] = {sv.x, sv.y, sv.z, sv.w};
#pragma unroll
        for (int kk = 0; kk < 4; kk++) {
            const float* wk  = &sW[(k4 + kk) * M + mBase];
            const float* wik = &sWi[(k4 + kk) * M + mBase];
#pragma unroll
            for (int m = 0; m < MT; m++)
                acc[m] = fmaf(a[kk], wk[m], fmaf(s[kk], wik[m], acc[m]));
        }
    }

    float vv[MT];
#pragma unroll
    for (int m = 0; m < MT; m++)
        vv[m] = fmaxf(acc[m] + b[mBase + m] + bi[mBase + m], 0.0f);

    float* orow = out + (size_t)r * M + mBase;
#pragma unroll
    for (int m = 0; m < MT; m++) orow[m] = vv[m];

    uint* brow = outB + (size_t)r * (M / 2) + (mBase >> 1);
#pragma unroll
    for (int m = 0; m < MT; m += 2)
        brow[m >> 1] = pack_bf16x2(vv[m], vv[m + 1]);
}

// Layer-2 fused GEMM restricted to sampled rows; S2 and out are compact.
__global__ __launch_bounds__(256) void gemm_fused2_sel(
    const float* __restrict__ Lx, const float* __restrict__ X,
    const float* __restrict__ S2c,
    const float* __restrict__ W, const float* __restrict__ b,
    const float* __restrict__ Wi, const float* __restrict__ bi,
    const int* __restrict__ userIdx, const int* __restrict__ itemIdx,
    float* __restrict__ outC)
{
    constexpr int K = 80, M = 50, TPR = 2, MT = M / TPR;
    __shared__ float sW[K * M];
    __shared__ float sWi[K * M];
    for (int i = threadIdx.x; i < K * M; i += 256) {
        sW[i]  = W[i];
        sWi[i] = Wi[i];
    }
    __syncthreads();

    int i = blockIdx.x * (256 / TPR) + (int)threadIdx.x / TPR;
    int mBase = ((int)threadIdx.x % TPR) * MT;
    if (i >= 2 * BATCH) return;
    int r = (i < BATCH) ? userIdx[i] : itemIdx[i - BATCH];

    const float* xrow = X + (size_t)r * K;
    const float* lrow = Lx + (size_t)r * K;
    const float* srow = S2c + (size_t)i * K;

    float acc[MT];
#pragma unroll
    for (int m = 0; m < MT; m++) acc[m] = 0.0f;

    for (int k4 = 0; k4 < K; k4 += 4) {
        float4 lv = *(const float4*)(lrow + k4);
        float4 xv = *(const float4*)(xrow + k4);
        float4 sv = *(const float4*)(srow + k4);
        float a[4] = {lv.x + xv.x, lv.y + xv.y, lv.z + xv.z, lv.w + xv.w};
        float s[4] = {sv.x, sv.y, sv.z, sv.w};
#pragma unroll
        for (int kk = 0; kk < 4; kk++) {
            const float* wk  = &sW[(k4 + kk) * M + mBase];
            const float* wik = &sWi[(k4 + kk) * M + mBase];
#pragma unroll
            for (int m = 0; m < MT; m++)
                acc[m] = fmaf(a[kk], wk[m], fmaf(s[kk], wik[m], acc[m]));
        }
    }

    float* orow = outC + (size_t)i * M + mBase;
#pragma unroll
    for (int m = 0; m < MT; m++)
        orow[m] = fmaxf(acc[m] + b[mBase + m] + bi[mBase + m], 0.0f);
}

// ------------- Plain MLP GEMM ---------------------------------------------
template<int K, int M, int TPR, bool RELU>
__global__ __launch_bounds__(256) void mlp_gemm(
    const float* __restrict__ A,
    const float* __restrict__ W, const float* __restrict__ b,
    float* __restrict__ out, int N)
{
    __shared__ float sW[K * M];
    for (int i = threadIdx.x; i < K * M; i += 256) sW[i] = W[i];
    __syncthreads();

    constexpr int RPB = 256 / TPR;
    constexpr int MT  = M / TPR;
    int r = blockIdx.x * RPB + (int)threadIdx.x / TPR;
    int mBase = ((int)threadIdx.x % TPR) * MT;
    if (r >= N) return;

    const float* arow = A + (size_t)r * K;
    float acc[MT];
#pragma unroll
    for (int m = 0; m < MT; m++) acc[m] = 0.0f;

    for (int k = 0; k < K; k++) {
        float a = arow[k];
#pragma unroll
        for (int m = 0; m < MT; m++)
            acc[m] = fmaf(a, sW[k * M + mBase + m], acc[m]);
    }

    float* orow = out + (size_t)r * M + mBase;
#pragma unroll
    for (int m = 0; m < MT; m++) {
        float vv = acc[m] + b[mBase + m];
        orow[m] = RELU ? fmaxf(vv, 0.0f) : vv;
    }
}

// ------------- Gather final embeddings into [BATCH, 460] ------------------
__global__ __launch_bounds__(128) void gather_embd(
    const int* __restrict__ userIdx, const int* __restrict__ itemIdx,
    const float* __restrict__ uE, const float* __restrict__ iE,
    const float* __restrict__ f1, const float* __restrict__ f2c,
    float* __restrict__ emb)
{
    int bi = blockIdx.x;
    int u  = userIdx[bi];
    int it = itemIdx[bi];
    float* orow = emb + (size_t)bi * 460;
    for (int c = threadIdx.x; c < 460; c += 128) {
        float val;
        if (c < 100) {
            val = (u < N_USERS) ? uE[(size_t)u * 100 + c]
                                : iE[(size_t)(u - N_USERS) * 100 + c];
        } else if (c < 180) {
            val = f1[(size_t)u * 80 + (c - 100)];
        } else if (c < 230) {
            val = f2c[(size_t)bi * 50 + (c - 180)];
        } else if (c < 330) {
            int cc = c - 230;
            val = (it < N_USERS) ? uE[(size_t)it * 100 + cc]
                                 : iE[(size_t)(it - N_USERS) * 100 + cc];
        } else if (c < 410) {
            val = f1[(size_t)it * 80 + (c - 330)];
        } else {
            val = f2c[(size_t)(BATCH + bi) * 50 + (c - 410)];
        }
        orow[c] = val;
    }
}

extern "C" void kernel_launch(void* const* d_in, const int* in_sizes, int n_in,
                              void* d_out, int out_size, void* d_ws, size_t ws_size,
                              hipStream_t stream) {
    const int*   userIdx = (const int*)d_in[0];
    const int*   itemIdx = (const int*)d_in[1];
    const int*   rows    = (const int*)d_in[2];
    const int*   cols    = (const int*)d_in[3];
    const float* vals    = (const float*)d_in[4];
    const float* uEmbd   = (const float*)d_in[5];
    const float* iEmbd   = (const float*)d_in[6];
    const float* w1      = (const float*)d_in[7];
    const float* b1      = (const float*)d_in[8];
    const float* wi1     = (const float*)d_in[9];
    const float* bi1     = (const float*)d_in[10];
    const float* w2      = (const float*)d_in[11];
    const float* b2      = (const float*)d_in[12];
    const float* wi2     = (const float*)d_in[13];
    const float* bi2     = (const float*)d_in[14];
    const float* t1w     = (const float*)d_in[15];
    const float* t1b     = (const float*)d_in[16];
    const float* t2w     = (const float*)d_in[17];
    const float* t2b     = (const float*)d_in[18];
    const float* t3w     = (const float*)d_in[19];
    const float* t3b     = (const float*)d_in[20];

    // ---- workspace layout (4-byte units), with aliasing ----
    float* ws = (float*)d_ws;
    float* B1   = ws;                          // 15,000,000
    float* B2   = ws + 15000000;               // 15,000,000
    float* F1   = ws + 30000000;               // 12,000,000 fp32
    uint*  INTb = (uint*)F1;                   //  7,500,000 (dead after pass 2)
    uint*  Xb   = (uint*)(ws + 42000000);      //  7,500,000 (dead after pass 1)
    uint*  F1b  = Xb;                          //  6,000,000 (written by gemm1)
    float* F2c  = B2;                          //   409,600
    float* B2c  = B2 + 409600;                 //   655,360
    float* EMB  = B2 + 1064960;                // 1,884,160
    float* H1   = B2 + 2949120;                //   262,144
    float* H2   = B2 + 3211264;                //   131,072
    int*   deg  = (int*)(ws + 49500000);       //   150,000
    int*   ptr  = deg + 150000;                //   150,000
    int*   pos  = ptr + 150000;                //   150,000
    int*   bsum = pos + 150000;                //     1,024
    int2*  ep   = (int2*)(bsum + 1024);        // 1,500,000 int2 (12 MB)
    int*   flag = (int*)(ep + 1500000);        //   150,000
    int*   fpre = flag + 150000;               //   150,000
    int*   list = fpre + 150000;               //   150,000
    int*   bsum2= list + 150000;               //     1,024
    int*   cnt  = bsum2 + 1024;                //         1

    const int E = N_EDGES;
    dim3 blk(256);

    // ---- bf16 feature cast ----
    cast_feats<<<(N_NODES * 50 + 255) / 256, blk, 0, stream>>>(uEmbd, iEmbd, Xb);

    // ---- CSR build ----
    hipMemsetAsync(deg, 0, 150000 * sizeof(int), stream);
    hipMemsetAsync(flag, 0, 150000 * sizeof(int), stream);
    hist_kernel<<<(E + 255) / 256, blk, 0, stream>>>(rows, deg, E);
    int nScanBlocks = (N_NODES + 255) / 256;            // 586
    scan_block<<<nScanBlocks, blk, 0, stream>>>(deg, ptr, bsum, N_NODES);
    scan_tops<<<1, dim3(1024), 0, stream>>>(bsum, nScanBlocks);
    scan_apply<<<nScanBlocks, blk, 0, stream>>>(ptr, bsum, pos, N_NODES);
    scatter_edges<<<(E + 255) / 256, blk, 0, stream>>>(rows, cols, vals, pos, ep, E);

    // ---- needed-row marking + compaction (for layer-2 pass 3) ----
    mark_needed<<<(2 * BATCH + 3) / 4, blk, 0, stream>>>(
        userIdx, itemIdx, ptr, deg, ep, flag);
    scan_block<<<nScanBlocks, blk, 0, stream>>>(flag, fpre, bsum2, N_NODES);
    scan_tops<<<1, dim3(1024), 0, stream>>>(bsum2, nScanBlocks);
    compact_list<<<nScanBlocks, blk, 0, stream>>>(flag, fpre, bsum2, list, cnt, N_NODES);

    int rowGrid = (N_NODES + 3) / 4;
    int selGrid = (2 * BATCH + 3) / 4;

    // ---- Layer 1 (F = 100) ----
    spmm_bf_epi<100><<<rowGrid, blk, 0, stream>>>(
        ptr, deg, ep, Xb, B1, INTb, N_NODES);
    spmm_bf<100><<<rowGrid, blk, 0, stream>>>(
        ptr, deg, ep, INTb, B2, N_NODES);
    {
        constexpr int TPR = 4;
        int grid = (N_NODES + 255) / 256;     // 256 rows per 1024-thread block
        gemm_fused1<100, 80, TPR><<<grid, dim3(1024), 0, stream>>>(
            B1, uEmbd, iEmbd, N_USERS, B2, w1, b1, wi1, bi1, F1, F1b, N_NODES);
    }

    // ---- Layer 2 (F = 80) ----
    spmm_bf_list<<<rowGrid, blk, 0, stream>>>(
        list, cnt, ptr, deg, ep, F1b, B1);
    spmm_sel<<<selGrid, blk, 0, stream>>>(
        ptr, deg, ep, B1, F1b, userIdx, itemIdx, B2c);
    {
        int grid = (2 * BATCH + 127) / 128;
        gemm_fused2_sel<<<grid, blk, 0, stream>>>(
            B1, F1, B2c, w2, b2, wi2, bi2, userIdx, itemIdx, F2c);
    }

    // ---- Gather + MLP ----
    gather_embd<<<BATCH, dim3(128), 0, stream>>>(
        userIdx, itemIdx, uEmbd, iEmbd, F1, F2c, EMB);
    {
        constexpr int TPR = 8;
        int grid = (BATCH + (256 / TPR) - 1) / (256 / TPR);
        mlp_gemm<460, 64, TPR, true><<<grid, blk, 0, stream>>>(
            EMB, t1w, t1b, H1, BATCH);
    }
    {
        constexpr int TPR = 4;
        int grid = (BATCH + (256 / TPR) - 1) / (256 / TPR);
        mlp_gemm<64, 32, TPR, false><<<grid, blk, 0, stream>>>(
            H1, t2w, t2b, H2, BATCH);
    }
    {
        constexpr int TPR = 1;
        int grid = (BATCH + 255) / 256;
        mlp_gemm<32, 1, TPR, false><<<grid, blk, 0, stream>>>(
            H2, t3w, t3b, (float*)d_out, BATCH);
    }
}